// Round 7
// baseline (1125.124 us; speedup 1.0000x reference)
//
#include <hip/hip_runtime.h>
#include <cstdint>

#define BB 16
#define DD 256
#define TT 2048
#define KK 8192
#define NN 32768            // BB*TT
#define QQ 8388608          // BB*DD*TT
typedef unsigned long long u64;

typedef __attribute__((ext_vector_type(8))) short short8;   // 8 bf16 (4 VGPRs)
typedef __attribute__((ext_vector_type(4))) float f32x4;    // MFMA C/D

#define GLOBAL_AS __attribute__((address_space(1)))
#define LDS_AS    __attribute__((address_space(3)))

// async global->LDS, 16 B per lane; LDS dest = wave-uniform base + lane*16
__device__ __forceinline__ void async_copy16(void* l, const void* g) {
    __builtin_amdgcn_global_load_lds((const GLOBAL_AS unsigned int*)g,
                                     (LDS_AS unsigned int*)l, 16, 0, 0);
}

__device__ __forceinline__ unsigned mapf(float f) {
    unsigned u = __float_as_uint(f);
    return (u & 0x80000000u) ? ~u : (u | 0x80000000u);
}
__device__ __forceinline__ float unmapf(unsigned u) {
    return __uint_as_float((u & 0x80000000u) ? (u & 0x7FFFFFFFu) : ~u);
}
__device__ __forceinline__ unsigned bf16_rne(float v) {
    unsigned ui = __float_as_uint(v);
    return (ui + 0x7FFFu + ((ui >> 16) & 1)) >> 16;
}

// ---------------------------------------------------------------------------
// A32[n] = fp32(fp64 sum of z_n^2); zero cnt & loss. grid 512 x 256
// ---------------------------------------------------------------------------
__global__ __launch_bounds__(256) void k_prepA(const float* __restrict__ z,
                                               float* __restrict__ A32,
                                               int* __restrict__ cnt,
                                               float* __restrict__ out) {
    __shared__ double sd[256];
    int tid = threadIdx.x;
    int r = tid & 63;               // row within block (coalesced over t)
    int c = tid >> 6;               // wave -> d quarter
    int n = blockIdx.x * 64 + r;
    if (blockIdx.x == 0 && tid == 0) { *cnt = 0; out[QQ] = 0.0f; }
    int b = n >> 11, t = n & 2047;
    const float* zp = z + (size_t)b * 524288 + t;
    double s = 0.0;
#pragma unroll 8
    for (int i = 0; i < 64; i++) {
        float v = zp[(size_t)(c * 64 + i) * 2048];
        s = fma((double)v, (double)v, s);
    }
    sd[tid] = s;
    __syncthreads();
    if (c == 0) {
        double tot = sd[r] + sd[64 + r] + sd[128 + r] + sd[192 + r];
        A32[n] = (float)tot;
    }
}

// ---------------------------------------------------------------------------
// z [b][d][t] fp32 -> zh/zl [n][d] bf16 hi/lo, 16B stores. grid 2048 x 256
// ---------------------------------------------------------------------------
__global__ __launch_bounds__(256) void k_convZ(const float* __restrict__ z,
                                               unsigned short* __restrict__ zh,
                                               unsigned short* __restrict__ zl) {
    __shared__ float sm[64][65];
    int tid = threadIdx.x;
    int bid = blockIdx.x;
    int b  = bid >> 7;
    int dt = (bid >> 5) & 3;
    int tt = bid & 31;
    const float* zp = z + (size_t)b * 524288 + (size_t)dt * 131072 + tt * 64;
#pragma unroll
    for (int i = 0; i < 16; i++) {
        int idx = tid + 256 * i;
        int d = idx >> 6, t = idx & 63;
        sm[d][t] = zp[(size_t)d * 2048 + t];
    }
    __syncthreads();
    int d0 = (tid & 7) * 8;
#pragma unroll
    for (int i = 0; i < 2; i++) {
        int t = (tid >> 3) + 32 * i;
        size_t o = ((size_t)(b * 2048 + tt * 64 + t)) * 256 + dt * 64 + d0;
        short8 hv, lv;
#pragma unroll
        for (int j = 0; j < 8; j++) {
            float v = sm[d0 + j][t];
            unsigned hb = bf16_rne(v);
            float hf = __uint_as_float(hb << 16);
            unsigned lb = bf16_rne(v - hf);
            hv[j] = (short)hb;
            lv[j] = (short)lb;
        }
        *(short8*)(zh + o) = hv;
        *(short8*)(zl + o) = lv;
    }
}

// ---------------------------------------------------------------------------
// emb [k][d] fp32 -> eh/el bf16 hi/lo. grid 1024 x 256
// ---------------------------------------------------------------------------
__global__ __launch_bounds__(256) void k_convE(const float* __restrict__ emb,
                                               unsigned short* __restrict__ eh,
                                               unsigned short* __restrict__ el) {
    int base = (blockIdx.x * 256 + threadIdx.x) * 8;
    float4 v0 = *(const float4*)(emb + base);
    float4 v1 = *(const float4*)(emb + base + 4);
    float vv[8] = {v0.x, v0.y, v0.z, v0.w, v1.x, v1.y, v1.z, v1.w};
    short8 hv, lv;
#pragma unroll
    for (int i = 0; i < 8; i++) {
        unsigned hb = bf16_rne(vv[i]);
        float hf = __uint_as_float(hb << 16);
        unsigned lb = bf16_rne(vv[i] - hf);
        hv[i] = (short)hb;
        lv[i] = (short)lb;
    }
    *(short8*)(eh + base) = hv;
    *(short8*)(el + base) = lv;
}

// ---------------------------------------------------------------------------
// MFMA distance GEMM v9: score = -2*(zh.eh + zh.el + zl.eh)
// v8 structure (proven): 256x1024 block, 512 threads / 8 waves, wave tile
// 64x128, all-LDS staging, BK=32 double-buffer (128 KB), single barrier per
// K-step with free vmcnt(0) drain (loads issued a full window earlier).
// CHANGE vs v8: per-lane top-2 tracks the INDEX of #2 again (candidate-list
// contract: select rescores {p1,p2} x 8ng exactly, so i2 is needed).
// grid 1024 (tl = (bid&7)*128 + bid>>3; mt = tl>>3, ng = tl&7).
// ---------------------------------------------------------------------------
__global__ __launch_bounds__(512, 2) void k_gemm(const unsigned short* __restrict__ zh,
                                                 const unsigned short* __restrict__ zl,
                                                 const unsigned short* __restrict__ eh,
                                                 const unsigned short* __restrict__ el,
                                                 u64* __restrict__ cand) {
    // per buffer (64 KB): zh tiles [0,8192), zl [8192,16384), eh [16384,24576),
    // el [24576,32768) shorts; tile = 16 rows x 32 k = 512 shorts, fragment-
    // major (slot l = 16B: row = l&15, k-chunk = l>>4). rtop (8 KB) aliases
    // pool[0] after the final barrier.
    __shared__ __align__(16) unsigned short pool[2][32768];   // 128 KB

    int tid  = threadIdx.x;
    int w    = __builtin_amdgcn_readfirstlane(tid >> 6);   // wave id (uniform)
    int lane = tid & 63;
    int lm   = lane & 15;
    int q    = lane >> 4;
    int wm   = w >> 1;              // 0..3: 64-row group
    int wn   = w & 1;               // 0..1: 128-code half

    int bid = blockIdx.x;
    int tl  = (bid & 7) * 128 + (bid >> 3);   // XCD-chunked (1024 % 8 == 0)
    int mt  = tl >> 3;              // 0..127: 256-row tile
    int ng  = tl & 7;               // 0..7  : 1024-code group

    // ---- staging: 8 copies/wave; slot = w*8+i -> (arr = slot>>4, tile = slot&15)
    int laneoff = lm * 256 + q * 8;          // per-lane (row, k-chunk) offset
    const unsigned short* gp[8];
    unsigned dlo[8];
    bool bflag[8];
#pragma unroll
    for (int i = 0; i < 8; i++) {
        int slot = w * 8 + i;
        int arr  = slot >> 4;
        int tile = slot & 15;
        const unsigned short* s = (arr == 0) ? zh : (arr == 1) ? zl
                                : (arr == 2) ? eh : el;
        int rowb = (arr < 2) ? mt * 256 : ng * 1024;
        gp[i]    = s + (size_t)(rowb + tile * 16) * 256 + laneoff;
        dlo[i]   = (unsigned)(arr * 8192 + tile * 512);
        bflag[i] = (arr >= 2);
    }

    // float-domain top-2 per (mi,reg): track MAX of acc (score = -2*acc),
    // with indices for BOTH (candidate-rescore contract).
    float v1a[4][4], v2a[4][4];
    int   i1a[4][4], i2a[4][4];
#pragma unroll
    for (int mi = 0; mi < 4; mi++)
#pragma unroll
        for (int reg = 0; reg < 4; reg++) {
            v1a[mi][reg] = -3.4e38f; v2a[mi][reg] = -3.4e38f;
            i1a[mi][reg] = 0;        i2a[mi][reg] = 0;
        }

    f32x4 acc[4][8];

    // prologue: stage k-tile 0 into buffer 0
#pragma unroll
    for (int i = 0; i < 8; i++)
        async_copy16(&pool[0][dlo[i]], gp[i]);

    for (int t = 0; t < 32; ++t) {            // 4 passes x 8 K-steps
        int buf = t & 1;
        int kc  = t & 7;

        // stage(t) was issued one full compute window ago -> drain is free
        asm volatile("s_waitcnt vmcnt(0)" ::: "memory");
        __builtin_amdgcn_s_barrier();          // buf complete + prior readers done
        __builtin_amdgcn_sched_barrier(0);

        int tn = t + 1;
        if (tn < 32) {
            if ((tn & 7) == 0) {               // next stage starts a new 256-code pass
#pragma unroll
                for (int i = 0; i < 8; i++)
                    if (bflag[i]) gp[i] += 65536;   // +256 codes
            }
            int nkc = tn & 7;
#pragma unroll
            for (int i = 0; i < 8; i++)
                async_copy16(&pool[buf ^ 1][dlo[i]], gp[i] + nkc * 32);
        }

        if (kc == 0) {
#pragma unroll
            for (int mi = 0; mi < 4; mi++)
#pragma unroll
                for (int ni = 0; ni < 8; ni++) acc[mi][ni] = (f32x4){0.f, 0.f, 0.f, 0.f};
        }

        const unsigned short* pb = pool[buf];
        short8 azh[4], azl[4];
#pragma unroll
        for (int mi = 0; mi < 4; mi++) {
            azh[mi] = *(const short8*)&pb[(wm * 4 + mi) * 512 + lane * 8];
            azl[mi] = *(const short8*)&pb[8192 + (wm * 4 + mi) * 512 + lane * 8];
        }
        __builtin_amdgcn_s_setprio(1);
#pragma unroll
        for (int ni = 0; ni < 8; ni++) {
            short8 bh = *(const short8*)&pb[16384 + (wn * 8 + ni) * 512 + lane * 8];
            short8 bl = *(const short8*)&pb[24576 + (wn * 8 + ni) * 512 + lane * 8];
#pragma unroll
            for (int mi = 0; mi < 4; mi++) {
                acc[mi][ni] = __builtin_amdgcn_mfma_f32_16x16x32_bf16(azh[mi], bh, acc[mi][ni], 0, 0, 0);
                acc[mi][ni] = __builtin_amdgcn_mfma_f32_16x16x32_bf16(azl[mi], bh, acc[mi][ni], 0, 0, 0);
                acc[mi][ni] = __builtin_amdgcn_mfma_f32_16x16x32_bf16(azh[mi], bl, acc[mi][ni], 0, 0, 0);
            }
        }
        __builtin_amdgcn_s_setprio(0);

        if (kc == 7) {   // pass complete: fold 256 codes into per-lane top-2
            int idb = ng * 1024 + (t >> 3) * 256 + wn * 128 + lm;
#pragma unroll
            for (int ni = 0; ni < 8; ni++) {
                int id = idb + ni * 16;
#pragma unroll
                for (int mi = 0; mi < 4; mi++)
#pragma unroll
                    for (int reg = 0; reg < 4; reg++) {
                        float v = acc[mi][ni][reg];
                        bool c2 = v > v2a[mi][reg];
                        bool c1 = v > v1a[mi][reg];
                        v2a[mi][reg] = c2 ? v  : v2a[mi][reg];
                        i2a[mi][reg] = c2 ? id : i2a[mi][reg];
                        v2a[mi][reg] = c1 ? v1a[mi][reg] : v2a[mi][reg];
                        i2a[mi][reg] = c1 ? i1a[mi][reg] : i2a[mi][reg];
                        v1a[mi][reg] = c1 ? v  : v1a[mi][reg];
                        i1a[mi][reg] = c1 ? id : i1a[mi][reg];
                    }
            }
        }
        // no end barrier: next iteration's top barrier protects the restage
    }

    // pack to mapf-u64, butterfly across the 16 lm-lanes (bits 0..3 of lane);
    // rtop aliases pool[0] (its last reads were fenced by the t=31 barrier).
    u64* rtop = (u64*)&pool[0][0];
#pragma unroll
    for (int mi = 0; mi < 4; mi++)
#pragma unroll
        for (int reg = 0; reg < 4; reg++) {
            u64 p1 = ((u64)mapf(-2.0f * v1a[mi][reg]) << 32) | (unsigned)i1a[mi][reg];
            u64 p2 = ((u64)mapf(-2.0f * v2a[mi][reg]) << 32) | (unsigned)i2a[mi][reg];
#pragma unroll
            for (int msk = 1; msk <= 8; msk <<= 1) {
                u64 q1 = __shfl_xor(p1, msk, 64);
                u64 q2 = __shfl_xor(p2, msk, 64);
                u64 n1 = (p1 < q1) ? p1 : q1;
                u64 hi = (p1 < q1) ? q1 : p1;
                u64 n2 = (q2 < p2) ? q2 : p2;
                n2 = (hi < n2) ? hi : n2;
                p1 = n1; p2 = n2;
            }
            if (lm == 0) {
                int rl = wm * 64 + mi * 16 + q * 4 + reg;   // 0..255 block row
                rtop[rl * 4 + wn * 2]     = p1;
                rtop[rl * 4 + wn * 2 + 1] = p2;
            }
        }
    __syncthreads();
    if (tid < 256) {   // merge the two code-halves for each row
        u64 a1 = rtop[tid * 4],     a2 = rtop[tid * 4 + 1];
        u64 b1 = rtop[tid * 4 + 2], b2 = rtop[tid * 4 + 3];
        u64 m1 = (a1 < b1) ? a1 : b1;
        u64 lo = (a1 < b1) ? b1 : a1;
        u64 m2 = (a2 < b2) ? a2 : b2;
        m2 = (lo < m2) ? lo : m2;
        size_t o = ((size_t)ng * 32768 + (size_t)mt * 256 + tid) * 2;
        cand[o]     = m1;
        cand[o + 1] = m2;
    }
}

// ---------------------------------------------------------------------------
// select v2 (candidate rescore): per row, the 8 per-ng (top1,top2) pairs give
// a 16-candidate shortlist. Soundness guard: if NO ng's 2nd-best bf-score is
// within W of the global bf-min, every code with bf-score <= f1+W is its ng's
// top-1 (at most one window code per ng) -> all fp32-minimal codes are in the
// shortlist (|bf - fp32| <= W/2). Then exact fp32 rescoring of the 16
// candidates in the REFERENCE accumulation order (serial fmaf, d ascending;
// dk = A32 - 2*acc) + lexicographic (dist,idx) min reproduces the full scan
// exactly. Guard violated (2 same-ng window codes, ~4% of rows) -> full
// k_refine. grid 128 x 256.
// ---------------------------------------------------------------------------
__global__ __launch_bounds__(256) void k_select(const u64* __restrict__ cand,
                                                const float* __restrict__ z,
                                                const float* __restrict__ emb,
                                                const float* __restrict__ A32,
                                                int* __restrict__ keys,
                                                int* __restrict__ cnt,
                                                int* __restrict__ list) {
    int n = blockIdx.x * 256 + threadIdx.x;
    u64 p1[8], p2[8];
    u64 m1 = ~0ull;
#pragma unroll
    for (int j = 0; j < 8; j++) {
        p1[j] = cand[((size_t)j * 32768 + n) * 2];
        p2[j] = cand[((size_t)j * 32768 + n) * 2 + 1];
        m1 = (p1[j] < m1) ? p1[j] : m1;
    }
    float f1   = unmapf((unsigned)(m1 >> 32));
    float A32v = A32[n];
    float W = ((A32v >= 255.9f) ? 3.4e-5f : 1.8e-5f) + 4e-6f;  // + 2*eps(bf16x3)

    bool flag = false;
#pragma unroll
    for (int j = 0; j < 8; j++)
        flag |= (unmapf((unsigned)(p2[j] >> 32)) - f1 <= W);

    if (flag) {
        keys[n] = (int)(unsigned)(m1 & 0xFFFFFFFFull);   // refine overwrites
        int p = atomicAdd(cnt, 1);
        list[p] = n;
        return;
    }

    // exact fp32 rescore of the 16 candidates (reference order)
    int idx[16];
#pragma unroll
    for (int j = 0; j < 8; j++) {
        idx[2 * j]     = (int)(unsigned)(p1[j] & 0xFFFFFFFFull);
        idx[2 * j + 1] = (int)(unsigned)(p2[j] & 0xFFFFFFFFull);
    }
    float acc[16];
#pragma unroll
    for (int c = 0; c < 16; c++) acc[c] = 0.0f;

    int b = n >> 11, t = n & 2047;
    const float* zp = z + (size_t)b * 524288 + t;
    for (int d = 0; d < 256; d++) {
        float zv = zp[(size_t)d * 2048];
#pragma unroll
        for (int c = 0; c < 16; c++)
            acc[c] = fmaf(zv, emb[(size_t)idx[c] * 256 + d], acc[c]);
    }
    u64 best = ~0ull;
#pragma unroll
    for (int c = 0; c < 16; c++) {
        float dk = A32v - 2.0f * acc[c];
        u64 p = ((u64)mapf(dk) << 32) | (unsigned)idx[c];
        best = (p < best) ? p : best;
    }
    keys[n] = (int)(unsigned)(best & 0xFFFFFFFFull);
}

// ---------------------------------------------------------------------------
// FALLBACK path (round-3 proven): fp32 VALU GEMM argmin + its select
// ---------------------------------------------------------------------------
__global__ __launch_bounds__(256) void k_argmin_fb(const float* __restrict__ z,
                                                   const float* __restrict__ emb,
                                                   u64* __restrict__ cand2) {
    __shared__ __align__(16) float smem[8192];
    float* As = smem;
    float* Bs = smem + 4096;

    int tid = threadIdx.x;
    int tx  = tid & 15;
    int ty  = tid >> 4;
    int mt  = blockIdx.x;
    int kh  = blockIdx.y;

    int bimg = mt >> 4;
    int t0   = (mt & 15) << 7;
    const float* zb = z + (size_t)bimg * (DD * TT) + t0;

    float bestv[8], bestv2[8];
    int   besti[8];
#pragma unroll
    for (int i = 0; i < 8; i++) { bestv[i] = 3.4e38f; bestv2[i] = 3.4e38f; besti[i] = 0; }

    int qa = tid & 31, ra = tid >> 5;
    int jb = tid >> 3, db = tid & 7;
    int swz_t = (tx & 7) << 2;

    for (int kc = 0; kc < 32; kc++) {
        int k0 = kh * 4096 + kc * 128;
        float acc[8][8];
#pragma unroll
        for (int i = 0; i < 8; i++)
#pragma unroll
            for (int j = 0; j < 8; j++) acc[i][j] = 0.0f;

        for (int dc = 0; dc < 8; dc++) {
            int d0 = dc * 32;
            __syncthreads();
#pragma unroll
            for (int s = 0; s < 4; s++) {
                int d = ra + 8 * s;
                float4 v = *(const float4*)(zb + (size_t)(d0 + d) * TT + 4 * qa);
                *(float4*)(As + d * 128 + 4 * qa) = v;
            }
#pragma unroll
            for (int s = 0; s < 4; s++) {
                int row = jb + 32 * s;
                float4 v = *(const float4*)(emb + (size_t)(k0 + row) * DD + d0 + 4 * db);
                int col  = (4 * db) ^ ((row & 7) << 2);
                *(float4*)(Bs + row * 32 + col) = v;
            }
            __syncthreads();
#pragma unroll
            for (int g = 0; g < 8; g++) {
                float4 bf[8];
#pragma unroll
                for (int in = 0; in < 8; in++) {
                    int nn = in * 16 + tx;
                    bf[in] = *(const float4*)(Bs + nn * 32 + ((4 * g) ^ swz_t));
                }
#pragma unroll
                for (int j = 0; j < 4; j++) {
                    int d = 4 * g + j;
                    float4 a0 = *(const float4*)(As + d * 128 + ty * 8);
                    float4 a1 = *(const float4*)(As + d * 128 + ty * 8 + 4);
                    float av[8] = {a0.x, a0.y, a0.z, a0.w, a1.x, a1.y, a1.z, a1.w};
#pragma unroll
                    for (int im = 0; im < 8; im++) {
#pragma unroll
                        for (int in = 0; in < 8; in++) {
                            const float* bfp = (const float*)&bf[in];
                            acc[im][in] = fmaf(av[im], bfp[j], acc[im][in]);
                        }
                    }
                }
            }
        }
#pragma unroll
        for (int in = 0; in < 8; in++) {
            int k = k0 + in * 16 + tx;
#pragma unroll
            for (int im = 0; im < 8; im++) {
                float s = -2.0f * acc[im][in];
                if (s < bestv[im]) { bestv2[im] = bestv[im]; bestv[im] = s; besti[im] = k; }
                else if (s < bestv2[im]) { bestv2[im] = s; }
            }
        }
    }

    __syncthreads();
    u64* red = (u64*)smem;
#pragma unroll
    for (int im = 0; im < 8; im++) {
        int r = ty * 8 + im;
        red[r * 32 + tx * 2 + 0] = ((u64)mapf(bestv[im]) << 32) | (unsigned)besti[im];
        red[r * 32 + tx * 2 + 1] = ((u64)mapf(bestv2[im]) << 32);
    }
    __syncthreads();
    if (tid < 128) {
        const u64* base = red + tid * 32;
        u64 p1 = base[0];
        u64 s2 = base[1];
#pragma unroll
        for (int t = 1; t < 16; t++) {
            u64 c1 = base[t * 2], c2 = base[t * 2 + 1];
            if (c1 < p1) { s2 = (p1 < s2) ? p1 : s2; p1 = c1; }
            else         { s2 = (c1 < s2) ? c1 : s2; }
            s2 = (c2 < s2) ? c2 : s2;
        }
        int n = mt * 128 + tid;
        cand2[(size_t)n * 4 + kh * 2]     = p1;
        cand2[(size_t)n * 4 + kh * 2 + 1] = s2;
    }
}

__global__ __launch_bounds__(256) void k_select_fb(const u64* __restrict__ cand2,
                                                   const float* __restrict__ A32,
                                                   int* __restrict__ keys,
                                                   int* __restrict__ cnt,
                                                   int* __restrict__ list) {
    int n = blockIdx.x * 256 + threadIdx.x;
    u64 a1 = cand2[(size_t)n * 4 + 0], a2 = cand2[(size_t)n * 4 + 1];
    u64 b1 = cand2[(size_t)n * 4 + 2], b2 = cand2[(size_t)n * 4 + 3];
    u64 m1 = (a1 < b1) ? a1 : b1;
    u64 lo = (a1 < b1) ? b1 : a1;
    u64 m2 = (a2 < b2) ? a2 : b2;
    m2 = (lo < m2) ? lo : m2;

    keys[n] = (int)(unsigned)(m1 & 0xFFFFFFFFull);
    float f1 = unmapf((unsigned)(m1 >> 32));
    float f2 = unmapf((unsigned)(m2 >> 32));
    float W = (A32[n] >= 255.9f) ? 3.4e-5f : 1.8e-5f;
    if (f2 - f1 <= W) {
        int p = atomicAdd(cnt, 1);
        list[p] = n;
    }
}

// ---------------------------------------------------------------------------
// exact np-fp32 emulation for flagged rows (round-3 proven). grid 512
// ---------------------------------------------------------------------------
__global__ __launch_bounds__(256) void k_refine(const float* __restrict__ z,
                                                const float* __restrict__ emb,
                                                const float* __restrict__ A32,
                                                const int* __restrict__ list,
                                                const int* __restrict__ cnt,
                                                int* __restrict__ keys) {
    __shared__ __align__(16) float zs[256][8];
    __shared__ float aA[8];
    __shared__ int   ln[8];
    __shared__ u64   wred[4 * 8];

    int tid = threadIdx.x, lane = tid & 63, w = tid >> 6;
    int count = *cnt;
    int ngroups = (count + 7) >> 3;

    for (int g = blockIdx.x; g < ngroups; g += gridDim.x) {
        __syncthreads();
#pragma unroll
        for (int r = 0; r < 8; r++) {
            int row = g * 8 + r;
            int n   = list[(row < count) ? row : 0];
            int b = n >> 11, t = n & 2047;
            zs[tid][r] = z[(size_t)b * (DD * TT) + (size_t)tid * TT + t];
            if (tid == 0) { ln[r] = (row < count) ? n : -1; aA[r] = A32[n]; }
        }
        __syncthreads();

        u64 best[8];
#pragma unroll
        for (int r = 0; r < 8; r++) best[r] = 0xFFFFFFFFFFFFFFFFull;

        float Ar[8];
#pragma unroll
        for (int r = 0; r < 8; r++) Ar[r] = aA[r];

        for (int c = 0; c < 8; c++) {
            int kbase = c * 1024 + tid;
            const float4* e0 = (const float4*)(emb + (size_t)(kbase)       * DD);
            const float4* e1 = (const float4*)(emb + (size_t)(kbase + 256) * DD);
            const float4* e2 = (const float4*)(emb + (size_t)(kbase + 512) * DD);
            const float4* e3 = (const float4*)(emb + (size_t)(kbase + 768) * DD);
            float acc[4][8];
#pragma unroll
            for (int qq = 0; qq < 4; qq++)
#pragma unroll
                for (int r = 0; r < 8; r++) acc[qq][r] = 0.0f;

            for (int d4 = 0; d4 < 64; d4++) {
                float4 v0 = e0[d4], v1 = e1[d4], v2 = e2[d4], v3 = e3[d4];
                const float* p0 = (const float*)&v0;
                const float* p1 = (const float*)&v1;
                const float* p2 = (const float*)&v2;
                const float* p3 = (const float*)&v3;
#pragma unroll
                for (int i = 0; i < 4; i++) {
                    int d = 4 * d4 + i;
                    float4 za = *(const float4*)&zs[d][0];
                    float4 zb2 = *(const float4*)&zs[d][4];
                    const float* zr  = (const float*)&za;
                    const float* zr2 = (const float*)&zb2;
#pragma unroll
                    for (int r = 0; r < 4; r++) {
                        acc[0][r]     = fmaf(zr[r],  p0[i], acc[0][r]);
                        acc[1][r]     = fmaf(zr[r],  p1[i], acc[1][r]);
                        acc[2][r]     = fmaf(zr[r],  p2[i], acc[2][r]);
                        acc[3][r]     = fmaf(zr[r],  p3[i], acc[3][r]);
                        acc[0][r + 4] = fmaf(zr2[r], p0[i], acc[0][r + 4]);
                        acc[1][r + 4] = fmaf(zr2[r], p1[i], acc[1][r + 4]);
                        acc[2][r + 4] = fmaf(zr2[r], p2[i], acc[2][r + 4]);
                        acc[3][r + 4] = fmaf(zr2[r], p3[i], acc[3][r + 4]);
                    }
                }
            }
#pragma unroll
            for (int qq = 0; qq < 4; qq++) {
                int k = kbase + qq * 256;
#pragma unroll
                for (int r = 0; r < 8; r++) {
                    float dk = Ar[r] - 2.0f * acc[qq][r];
                    u64 p = ((u64)mapf(dk) << 32) | (unsigned)k;
                    best[r] = (p < best[r]) ? p : best[r];
                }
            }
        }
#pragma unroll
        for (int r = 0; r < 8; r++) {
            u64 v = best[r];
            for (int off = 32; off; off >>= 1) {
                u64 o = __shfl_down(v, off, 64);
                v = (o < v) ? o : v;
            }
            if (lane == 0) wred[w * 8 + r] = v;
        }
        __syncthreads();
        if (tid < 8) {
            u64 v = wred[tid];
#pragma unroll
            for (int j = 1; j < 4; j++) {
                u64 o = wred[j * 8 + tid];
                v = (o < v) ? o : v;
            }
            int n = ln[tid];
            if (n >= 0) keys[n] = (int)(unsigned)(v & 0xFFFFFFFFull);
        }
        __syncthreads();
    }
}

// ---------------------------------------------------------------------------
// gather quantized, write outputs, loss = 1.25 * mean((q - z)^2)
// ---------------------------------------------------------------------------
__global__ __launch_bounds__(256) void k_out(const float* __restrict__ z,
                                             const float* __restrict__ emb,
                                             const int* __restrict__ keys,
                                             float* __restrict__ out) {
    int tid = threadIdx.x;
    int n   = blockIdx.x * 256 + tid;
    int b   = n >> 11;
    int t   = n & 2047;
    int idx = keys[n];
    out[QQ + 1 + n] = (float)idx;

    const float4* erow = (const float4*)(emb + (size_t)idx * DD);
    const float*  zp   = z   + (size_t)b * (DD * TT) + t;
    float*        op   = out + (size_t)b * (DD * TT) + t;

    float ssd = 0.0f;
#pragma unroll 4
    for (int d4 = 0; d4 < 64; d4++) {
        float4 qv = erow[d4];
        float qa[4] = {qv.x, qv.y, qv.z, qv.w};
#pragma unroll
        for (int r = 0; r < 4; r++) {
            int d = 4 * d4 + r;
            float zv = zp[(size_t)d * TT];
            float df = qa[r] - zv;
            ssd = fmaf(df, df, ssd);
            op[(size_t)d * TT] = qa[r];
        }
    }
    for (int off = 32; off; off >>= 1) ssd += __shfl_down(ssd, off, 64);
    __shared__ float red[4];
    if ((tid & 63) == 0) red[tid >> 6] = ssd;
    __syncthreads();
    if (tid == 0) {
        float tot = red[0] + red[1] + red[2] + red[3];
        atomicAdd(out + QQ, tot * (1.25f / (float)QQ));
    }
}

// ---------------------------------------------------------------------------
extern "C" void kernel_launch(void* const* d_in, const int* in_sizes, int n_in,
                              void* d_out, int out_size, void* d_ws, size_t ws_size,
                              hipStream_t stream) {
    const float* z   = (const float*)d_in[0];   // [16, 256, 2048]
    const float* emb = (const float*)d_in[1];   // [8192, 256]
    float* out = (float*)d_out;

    char* ws = (char*)d_ws;
    const size_t oZH = 0;
    const size_t oZL = oZH + 16777216;
    const size_t oEH = oZL + 16777216;
    const size_t oEL = oEH + 4194304;
    const size_t oCD = oEL + 4194304;          // cand: 8*32768*2*8 = 4 MB
    const size_t oA3 = oCD + 4194304;
    const size_t oKY = oA3 + 131072;
    const size_t oLS = oKY + 131072;
    const size_t oCN = oLS + 131072;
    const size_t needed = oCN + 64;

    if (ws_size >= needed) {
        unsigned short* zh = (unsigned short*)(ws + oZH);
        unsigned short* zl = (unsigned short*)(ws + oZL);
        unsigned short* eh = (unsigned short*)(ws + oEH);
        unsigned short* el = (unsigned short*)(ws + oEL);
        u64*   cand = (u64*)(ws + oCD);
        float* A32  = (float*)(ws + oA3);
        int*   keys = (int*)(ws + oKY);
        int*   list = (int*)(ws + oLS);
        int*   cnt  = (int*)(ws + oCN);

        k_prepA <<<512,  256, 0, stream>>>(z, A32, cnt, out);
        k_convZ <<<2048, 256, 0, stream>>>(z, zh, zl);
        k_convE <<<1024, 256, 0, stream>>>(emb, eh, el);
        k_gemm  <<<1024, 512, 0, stream>>>(zh, zl, eh, el, cand);
        k_select<<<128,  256, 0, stream>>>(cand, z, emb, A32, keys, cnt, list);
        k_refine<<<512,  256, 0, stream>>>(z, emb, A32, list, cnt, keys);
        k_out   <<<128,  256, 0, stream>>>(z, emb, keys, out);
    } else {
        // fallback: round-3 proven path (~1.5 MB ws)
        u64*   cand2 = (u64*)ws;                          // 1 MB
        float* A32   = (float*)(ws + 1048576);            // 128 KB
        int*   keys  = (int*)(ws + 1048576 + 131072);
        int*   list  = (int*)(ws + 1048576 + 262144);
        int*   cnt   = (int*)(ws + 1048576 + 393216);

        k_prepA    <<<512,          256, 0, stream>>>(z, A32, cnt, out);
        k_argmin_fb<<<dim3(256, 2), 256, 0, stream>>>(z, emb, cand2);
        k_select_fb<<<128,          256, 0, stream>>>(cand2, A32, keys, cnt, list);
        k_refine   <<<512,          256, 0, stream>>>(z, emb, A32, list, cnt, keys);
        k_out      <<<128,          256, 0, stream>>>(z, emb, keys, out);
    }
}

// Round 8
// 929.951 us; speedup vs baseline: 1.2099x; 1.2099x over previous
//
#include <hip/hip_runtime.h>
#include <cstdint>

#define BB 16
#define DD 256
#define TT 2048
#define KK 8192
#define NN 32768            // BB*TT
#define QQ 8388608          // BB*DD*TT
typedef unsigned long long u64;

typedef __attribute__((ext_vector_type(8))) short short8;   // 8 bf16 (4 VGPRs)
typedef __attribute__((ext_vector_type(4))) float f32x4;    // MFMA C/D

#define GLOBAL_AS __attribute__((address_space(1)))
#define LDS_AS    __attribute__((address_space(3)))

// async global->LDS, 16 B per lane; LDS dest = wave-uniform base + lane*16
__device__ __forceinline__ void async_copy16(void* l, const void* g) {
    __builtin_amdgcn_global_load_lds((const GLOBAL_AS unsigned int*)g,
                                     (LDS_AS unsigned int*)l, 16, 0, 0);
}

__device__ __forceinline__ unsigned mapf(float f) {
    unsigned u = __float_as_uint(f);
    return (u & 0x80000000u) ? ~u : (u | 0x80000000u);
}
__device__ __forceinline__ float unmapf(unsigned u) {
    return __uint_as_float((u & 0x80000000u) ? (u & 0x7FFFFFFFu) : ~u);
}
__device__ __forceinline__ unsigned bf16_rne(float v) {
    unsigned ui = __float_as_uint(v);
    return (ui + 0x7FFFu + ((ui >> 16) & 1)) >> 16;
}

// ---------------------------------------------------------------------------
// A32[n] = fp32(fp64 sum of z_n^2); zero cnt & loss. grid 512 x 256
// ---------------------------------------------------------------------------
__global__ __launch_bounds__(256) void k_prepA(const float* __restrict__ z,
                                               float* __restrict__ A32,
                                               int* __restrict__ cnt,
                                               float* __restrict__ out) {
    __shared__ double sd[256];
    int tid = threadIdx.x;
    int r = tid & 63;               // row within block (coalesced over t)
    int c = tid >> 6;               // wave -> d quarter
    int n = blockIdx.x * 64 + r;
    if (blockIdx.x == 0 && tid == 0) { *cnt = 0; out[QQ] = 0.0f; }
    int b = n >> 11, t = n & 2047;
    const float* zp = z + (size_t)b * 524288 + t;
    double s = 0.0;
#pragma unroll 8
    for (int i = 0; i < 64; i++) {
        float v = zp[(size_t)(c * 64 + i) * 2048];
        s = fma((double)v, (double)v, s);
    }
    sd[tid] = s;
    __syncthreads();
    if (c == 0) {
        double tot = sd[r] + sd[64 + r] + sd[128 + r] + sd[192 + r];
        A32[n] = (float)tot;
    }
}

// ---------------------------------------------------------------------------
// z [b][d][t] fp32 -> zh/zl [n][d] bf16 hi/lo, 16B stores. grid 2048 x 256
// ---------------------------------------------------------------------------
__global__ __launch_bounds__(256) void k_convZ(const float* __restrict__ z,
                                               unsigned short* __restrict__ zh,
                                               unsigned short* __restrict__ zl) {
    __shared__ float sm[64][65];
    int tid = threadIdx.x;
    int bid = blockIdx.x;
    int b  = bid >> 7;
    int dt = (bid >> 5) & 3;
    int tt = bid & 31;
    const float* zp = z + (size_t)b * 524288 + (size_t)dt * 131072 + tt * 64;
#pragma unroll
    for (int i = 0; i < 16; i++) {
        int idx = tid + 256 * i;
        int d = idx >> 6, t = idx & 63;
        sm[d][t] = zp[(size_t)d * 2048 + t];
    }
    __syncthreads();
    int d0 = (tid & 7) * 8;
#pragma unroll
    for (int i = 0; i < 2; i++) {
        int t = (tid >> 3) + 32 * i;
        size_t o = ((size_t)(b * 2048 + tt * 64 + t)) * 256 + dt * 64 + d0;
        short8 hv, lv;
#pragma unroll
        for (int j = 0; j < 8; j++) {
            float v = sm[d0 + j][t];
            unsigned hb = bf16_rne(v);
            float hf = __uint_as_float(hb << 16);
            unsigned lb = bf16_rne(v - hf);
            hv[j] = (short)hb;
            lv[j] = (short)lb;
        }
        *(short8*)(zh + o) = hv;
        *(short8*)(zl + o) = lv;
    }
}

// ---------------------------------------------------------------------------
// emb [k][d] fp32 -> eh/el bf16 hi/lo. grid 1024 x 256
// ---------------------------------------------------------------------------
__global__ __launch_bounds__(256) void k_convE(const float* __restrict__ emb,
                                               unsigned short* __restrict__ eh,
                                               unsigned short* __restrict__ el) {
    int base = (blockIdx.x * 256 + threadIdx.x) * 8;
    float4 v0 = *(const float4*)(emb + base);
    float4 v1 = *(const float4*)(emb + base + 4);
    float vv[8] = {v0.x, v0.y, v0.z, v0.w, v1.x, v1.y, v1.z, v1.w};
    short8 hv, lv;
#pragma unroll
    for (int i = 0; i < 8; i++) {
        unsigned hb = bf16_rne(vv[i]);
        float hf = __uint_as_float(hb << 16);
        unsigned lb = bf16_rne(vv[i] - hf);
        hv[i] = (short)hb;
        lv[i] = (short)lb;
    }
    *(short8*)(eh + base) = hv;
    *(short8*)(el + base) = lv;
}

// ---------------------------------------------------------------------------
// MFMA distance GEMM v9 (unchanged from round 7): score = -2*(zh.eh+zh.el+zl.eh)
// 256x1024 block, 512 threads / 8 waves, wave tile 64x128, all-LDS staging,
// BK=32 double-buffer (128 KB), single barrier per K-step. Top-2 with both
// indices (candidate-rescore contract).
// grid 1024 (tl = (bid&7)*128 + bid>>3; mt = tl>>3, ng = tl&7).
// ---------------------------------------------------------------------------
__global__ __launch_bounds__(512, 2) void k_gemm(const unsigned short* __restrict__ zh,
                                                 const unsigned short* __restrict__ zl,
                                                 const unsigned short* __restrict__ eh,
                                                 const unsigned short* __restrict__ el,
                                                 u64* __restrict__ cand) {
    __shared__ __align__(16) unsigned short pool[2][32768];   // 128 KB

    int tid  = threadIdx.x;
    int w    = __builtin_amdgcn_readfirstlane(tid >> 6);   // wave id (uniform)
    int lane = tid & 63;
    int lm   = lane & 15;
    int q    = lane >> 4;
    int wm   = w >> 1;              // 0..3: 64-row group
    int wn   = w & 1;               // 0..1: 128-code half

    int bid = blockIdx.x;
    int tl  = (bid & 7) * 128 + (bid >> 3);   // XCD-chunked (1024 % 8 == 0)
    int mt  = tl >> 3;              // 0..127: 256-row tile
    int ng  = tl & 7;               // 0..7  : 1024-code group

    // ---- staging: 8 copies/wave; slot = w*8+i -> (arr = slot>>4, tile = slot&15)
    int laneoff = lm * 256 + q * 8;          // per-lane (row, k-chunk) offset
    const unsigned short* gp[8];
    unsigned dlo[8];
    bool bflag[8];
#pragma unroll
    for (int i = 0; i < 8; i++) {
        int slot = w * 8 + i;
        int arr  = slot >> 4;
        int tile = slot & 15;
        const unsigned short* s = (arr == 0) ? zh : (arr == 1) ? zl
                                : (arr == 2) ? eh : el;
        int rowb = (arr < 2) ? mt * 256 : ng * 1024;
        gp[i]    = s + (size_t)(rowb + tile * 16) * 256 + laneoff;
        dlo[i]   = (unsigned)(arr * 8192 + tile * 512);
        bflag[i] = (arr >= 2);
    }

    // float-domain top-2 per (mi,reg): track MAX of acc (score = -2*acc),
    // with indices for BOTH (candidate-rescore contract).
    float v1a[4][4], v2a[4][4];
    int   i1a[4][4], i2a[4][4];
#pragma unroll
    for (int mi = 0; mi < 4; mi++)
#pragma unroll
        for (int reg = 0; reg < 4; reg++) {
            v1a[mi][reg] = -3.4e38f; v2a[mi][reg] = -3.4e38f;
            i1a[mi][reg] = 0;        i2a[mi][reg] = 0;
        }

    f32x4 acc[4][8];

    // prologue: stage k-tile 0 into buffer 0
#pragma unroll
    for (int i = 0; i < 8; i++)
        async_copy16(&pool[0][dlo[i]], gp[i]);

    for (int t = 0; t < 32; ++t) {            // 4 passes x 8 K-steps
        int buf = t & 1;
        int kc  = t & 7;

        // stage(t) was issued one full compute window ago -> drain is cheap
        asm volatile("s_waitcnt vmcnt(0)" ::: "memory");
        __builtin_amdgcn_s_barrier();          // buf complete + prior readers done
        __builtin_amdgcn_sched_barrier(0);

        int tn = t + 1;
        if (tn < 32) {
            if ((tn & 7) == 0) {               // next stage starts a new 256-code pass
#pragma unroll
                for (int i = 0; i < 8; i++)
                    if (bflag[i]) gp[i] += 65536;   // +256 codes
            }
            int nkc = tn & 7;
#pragma unroll
            for (int i = 0; i < 8; i++)
                async_copy16(&pool[buf ^ 1][dlo[i]], gp[i] + nkc * 32);
        }

        if (kc == 0) {
#pragma unroll
            for (int mi = 0; mi < 4; mi++)
#pragma unroll
                for (int ni = 0; ni < 8; ni++) acc[mi][ni] = (f32x4){0.f, 0.f, 0.f, 0.f};
        }

        const unsigned short* pb = pool[buf];
        short8 azh[4], azl[4];
#pragma unroll
        for (int mi = 0; mi < 4; mi++) {
            azh[mi] = *(const short8*)&pb[(wm * 4 + mi) * 512 + lane * 8];
            azl[mi] = *(const short8*)&pb[8192 + (wm * 4 + mi) * 512 + lane * 8];
        }
        __builtin_amdgcn_s_setprio(1);
#pragma unroll
        for (int ni = 0; ni < 8; ni++) {
            short8 bh = *(const short8*)&pb[16384 + (wn * 8 + ni) * 512 + lane * 8];
            short8 bl = *(const short8*)&pb[24576 + (wn * 8 + ni) * 512 + lane * 8];
#pragma unroll
            for (int mi = 0; mi < 4; mi++) {
                acc[mi][ni] = __builtin_amdgcn_mfma_f32_16x16x32_bf16(azh[mi], bh, acc[mi][ni], 0, 0, 0);
                acc[mi][ni] = __builtin_amdgcn_mfma_f32_16x16x32_bf16(azl[mi], bh, acc[mi][ni], 0, 0, 0);
                acc[mi][ni] = __builtin_amdgcn_mfma_f32_16x16x32_bf16(azh[mi], bl, acc[mi][ni], 0, 0, 0);
            }
        }
        __builtin_amdgcn_s_setprio(0);

        if (kc == 7) {   // pass complete: fold 256 codes into per-lane top-2
            int idb = ng * 1024 + (t >> 3) * 256 + wn * 128 + lm;
#pragma unroll
            for (int ni = 0; ni < 8; ni++) {
                int id = idb + ni * 16;
#pragma unroll
                for (int mi = 0; mi < 4; mi++)
#pragma unroll
                    for (int reg = 0; reg < 4; reg++) {
                        float v = acc[mi][ni][reg];
                        bool c2 = v > v2a[mi][reg];
                        bool c1 = v > v1a[mi][reg];
                        v2a[mi][reg] = c2 ? v  : v2a[mi][reg];
                        i2a[mi][reg] = c2 ? id : i2a[mi][reg];
                        v2a[mi][reg] = c1 ? v1a[mi][reg] : v2a[mi][reg];
                        i2a[mi][reg] = c1 ? i1a[mi][reg] : i2a[mi][reg];
                        v1a[mi][reg] = c1 ? v  : v1a[mi][reg];
                        i1a[mi][reg] = c1 ? id : i1a[mi][reg];
                    }
            }
        }
        // no end barrier: next iteration's top barrier protects the restage
    }

    // pack to mapf-u64, butterfly across the 16 lm-lanes (bits 0..3 of lane);
    // rtop aliases pool[0] (its last reads were fenced by the t=31 barrier).
    u64* rtop = (u64*)&pool[0][0];
#pragma unroll
    for (int mi = 0; mi < 4; mi++)
#pragma unroll
        for (int reg = 0; reg < 4; reg++) {
            u64 p1 = ((u64)mapf(-2.0f * v1a[mi][reg]) << 32) | (unsigned)i1a[mi][reg];
            u64 p2 = ((u64)mapf(-2.0f * v2a[mi][reg]) << 32) | (unsigned)i2a[mi][reg];
#pragma unroll
            for (int msk = 1; msk <= 8; msk <<= 1) {
                u64 q1 = __shfl_xor(p1, msk, 64);
                u64 q2 = __shfl_xor(p2, msk, 64);
                u64 n1 = (p1 < q1) ? p1 : q1;
                u64 hi = (p1 < q1) ? q1 : p1;
                u64 n2 = (q2 < p2) ? q2 : p2;
                n2 = (hi < n2) ? hi : n2;
                p1 = n1; p2 = n2;
            }
            if (lm == 0) {
                int rl = wm * 64 + mi * 16 + q * 4 + reg;   // 0..255 block row
                rtop[rl * 4 + wn * 2]     = p1;
                rtop[rl * 4 + wn * 2 + 1] = p2;
            }
        }
    __syncthreads();
    if (tid < 256) {   // merge the two code-halves for each row
        u64 a1 = rtop[tid * 4],     a2 = rtop[tid * 4 + 1];
        u64 b1 = rtop[tid * 4 + 2], b2 = rtop[tid * 4 + 3];
        u64 m1 = (a1 < b1) ? a1 : b1;
        u64 lo = (a1 < b1) ? b1 : a1;
        u64 m2 = (a2 < b2) ? a2 : b2;
        m2 = (lo < m2) ? lo : m2;
        size_t o = ((size_t)ng * 32768 + (size_t)mt * 256 + tid) * 2;
        cand[o]     = m1;
        cand[o + 1] = m2;
    }
}

// ---------------------------------------------------------------------------
// select v3 (lane-parallel candidate rescore): 16 lanes per row, lane c owns
// candidate c of the 16-entry shortlist ({p1,p2} x 8 ng). Same soundness
// guard and W as v2 (proven round 7); rescore is the SAME serial-d fmaf chain
// per candidate (bit-exact reference order), just one candidate per lane.
// Group reductions via 16-lane shfl_xor. grid 2048 x 256 (16 rows/block,
// 8 blocks/CU -> 32 waves/CU to hide the emb gather latency).
// ---------------------------------------------------------------------------
__global__ __launch_bounds__(256) void k_select(const u64* __restrict__ cand,
                                                const float* __restrict__ z,
                                                const float* __restrict__ emb,
                                                const float* __restrict__ A32,
                                                int* __restrict__ keys,
                                                int* __restrict__ cnt,
                                                int* __restrict__ list) {
    int tid = threadIdx.x;
    int g   = tid >> 4;              // row group within block (0..15)
    int c   = tid & 15;              // candidate slot (0..15)
    int n   = blockIdx.x * 16 + g;

    // entry c: pair j = c>>1 (ng), element c&1 (p1/p2)
    u64 e = cand[((size_t)(c >> 1) * 32768 + n) * 2 + (c & 1)];

    // group-min over all 16 entries = global bf top-1 (p1 <= p2 within a pair)
    u64 m1 = e;
#pragma unroll
    for (int m = 1; m < 16; m <<= 1) {
        u64 o = __shfl_xor(m1, m, 64);
        m1 = (o < m1) ? o : m1;
    }
    float f1   = unmapf((unsigned)(m1 >> 32));
    float A32v = A32[n];
    float W = ((A32v >= 255.9f) ? 3.4e-5f : 1.8e-5f) + 4e-6f;  // + 2*eps(bf16x3)

    // guard: any ng's 2nd-best within W of global min -> full refine
    int fl = ((c & 1) && (unmapf((unsigned)(e >> 32)) - f1 <= W)) ? 1 : 0;
#pragma unroll
    for (int m = 1; m < 16; m <<= 1) fl |= __shfl_xor(fl, m, 64);

    if (fl) {
        if (c == 0) {
            keys[n] = (int)(unsigned)(m1 & 0xFFFFFFFFull);   // refine overwrites
            int p = atomicAdd(cnt, 1);
            list[p] = n;
        }
        return;
    }

    // exact fp32 rescore of candidate c (reference order: serial fmaf, d asc)
    int idx = (int)(unsigned)(e & 0xFFFFFFFFull);
    int b = n >> 11, t = n & 2047;
    const float* zp = z + (size_t)b * 524288 + t;
    const float* ep = emb + (size_t)idx * 256;
    float acc = 0.0f;
#pragma unroll 4
    for (int d = 0; d < 256; d++)
        acc = fmaf(zp[(size_t)d * 2048], ep[d], acc);
    float dk = A32v - 2.0f * acc;
    u64 best = ((u64)mapf(dk) << 32) | (unsigned)idx;
#pragma unroll
    for (int m = 1; m < 16; m <<= 1) {
        u64 o = __shfl_xor(best, m, 64);
        best = (o < best) ? o : best;
    }
    if (c == 0) keys[n] = (int)(unsigned)(best & 0xFFFFFFFFull);
}

// ---------------------------------------------------------------------------
// FALLBACK path (round-3 proven): fp32 VALU GEMM argmin + its select
// ---------------------------------------------------------------------------
__global__ __launch_bounds__(256) void k_argmin_fb(const float* __restrict__ z,
                                                   const float* __restrict__ emb,
                                                   u64* __restrict__ cand2) {
    __shared__ __align__(16) float smem[8192];
    float* As = smem;
    float* Bs = smem + 4096;

    int tid = threadIdx.x;
    int tx  = tid & 15;
    int ty  = tid >> 4;
    int mt  = blockIdx.x;
    int kh  = blockIdx.y;

    int bimg = mt >> 4;
    int t0   = (mt & 15) << 7;
    const float* zb = z + (size_t)bimg * (DD * TT) + t0;

    float bestv[8], bestv2[8];
    int   besti[8];
#pragma unroll
    for (int i = 0; i < 8; i++) { bestv[i] = 3.4e38f; bestv2[i] = 3.4e38f; besti[i] = 0; }

    int qa = tid & 31, ra = tid >> 5;
    int jb = tid >> 3, db = tid & 7;
    int swz_t = (tx & 7) << 2;

    for (int kc = 0; kc < 32; kc++) {
        int k0 = kh * 4096 + kc * 128;
        float acc[8][8];
#pragma unroll
        for (int i = 0; i < 8; i++)
#pragma unroll
            for (int j = 0; j < 8; j++) acc[i][j] = 0.0f;

        for (int dc = 0; dc < 8; dc++) {
            int d0 = dc * 32;
            __syncthreads();
#pragma unroll
            for (int s = 0; s < 4; s++) {
                int d = ra + 8 * s;
                float4 v = *(const float4*)(zb + (size_t)(d0 + d) * TT + 4 * qa);
                *(float4*)(As + d * 128 + 4 * qa) = v;
            }
#pragma unroll
            for (int s = 0; s < 4; s++) {
                int row = jb + 32 * s;
                float4 v = *(const float4*)(emb + (size_t)(k0 + row) * DD + d0 + 4 * db);
                int col  = (4 * db) ^ ((row & 7) << 2);
                *(float4*)(Bs + row * 32 + col) = v;
            }
            __syncthreads();
#pragma unroll
            for (int g = 0; g < 8; g++) {
                float4 bf[8];
#pragma unroll
                for (int in = 0; in < 8; in++) {
                    int nn = in * 16 + tx;
                    bf[in] = *(const float4*)(Bs + nn * 32 + ((4 * g) ^ swz_t));
                }
#pragma unroll
                for (int j = 0; j < 4; j++) {
                    int d = 4 * g + j;
                    float4 a0 = *(const float4*)(As + d * 128 + ty * 8);
                    float4 a1 = *(const float4*)(As + d * 128 + ty * 8 + 4);
                    float av[8] = {a0.x, a0.y, a0.z, a0.w, a1.x, a1.y, a1.z, a1.w};
#pragma unroll
                    for (int im = 0; im < 8; im++) {
#pragma unroll
                        for (int in = 0; in < 8; in++) {
                            const float* bfp = (const float*)&bf[in];
                            acc[im][in] = fmaf(av[im], bfp[j], acc[im][in]);
                        }
                    }
                }
            }
        }
#pragma unroll
        for (int in = 0; in < 8; in++) {
            int k = k0 + in * 16 + tx;
#pragma unroll
            for (int im = 0; im < 8; im++) {
                float s = -2.0f * acc[im][in];
                if (s < bestv[im]) { bestv2[im] = bestv[im]; bestv[im] = s; besti[im] = k; }
                else if (s < bestv2[im]) { bestv2[im] = s; }
            }
        }
    }

    __syncthreads();
    u64* red = (u64*)smem;
#pragma unroll
    for (int im = 0; im < 8; im++) {
        int r = ty * 8 + im;
        red[r * 32 + tx * 2 + 0] = ((u64)mapf(bestv[im]) << 32) | (unsigned)besti[im];
        red[r * 32 + tx * 2 + 1] = ((u64)mapf(bestv2[im]) << 32);
    }
    __syncthreads();
    if (tid < 128) {
        const u64* base = red + tid * 32;
        u64 p1 = base[0];
        u64 s2 = base[1];
#pragma unroll
        for (int t = 1; t < 16; t++) {
            u64 c1 = base[t * 2], c2 = base[t * 2 + 1];
            if (c1 < p1) { s2 = (p1 < s2) ? p1 : s2; p1 = c1; }
            else         { s2 = (c1 < s2) ? c1 : s2; }
            s2 = (c2 < s2) ? c2 : s2;
        }
        int n = mt * 128 + tid;
        cand2[(size_t)n * 4 + kh * 2]     = p1;
        cand2[(size_t)n * 4 + kh * 2 + 1] = s2;
    }
}

__global__ __launch_bounds__(256) void k_select_fb(const u64* __restrict__ cand2,
                                                   const float* __restrict__ A32,
                                                   int* __restrict__ keys,
                                                   int* __restrict__ cnt,
                                                   int* __restrict__ list) {
    int n = blockIdx.x * 256 + threadIdx.x;
    u64 a1 = cand2[(size_t)n * 4 + 0], a2 = cand2[(size_t)n * 4 + 1];
    u64 b1 = cand2[(size_t)n * 4 + 2], b2 = cand2[(size_t)n * 4 + 3];
    u64 m1 = (a1 < b1) ? a1 : b1;
    u64 lo = (a1 < b1) ? b1 : a1;
    u64 m2 = (a2 < b2) ? a2 : b2;
    m2 = (lo < m2) ? lo : m2;

    keys[n] = (int)(unsigned)(m1 & 0xFFFFFFFFull);
    float f1 = unmapf((unsigned)(m1 >> 32));
    float f2 = unmapf((unsigned)(m2 >> 32));
    float W = (A32[n] >= 255.9f) ? 3.4e-5f : 1.8e-5f;
    if (f2 - f1 <= W) {
        int p = atomicAdd(cnt, 1);
        list[p] = n;
    }
}

// ---------------------------------------------------------------------------
// exact np-fp32 emulation for flagged rows (round-3 proven; +unroll 2 for
// load pipelining — per-accumulator fmaf order unchanged). grid 512
// ---------------------------------------------------------------------------
__global__ __launch_bounds__(256) void k_refine(const float* __restrict__ z,
                                                const float* __restrict__ emb,
                                                const float* __restrict__ A32,
                                                const int* __restrict__ list,
                                                const int* __restrict__ cnt,
                                                int* __restrict__ keys) {
    __shared__ __align__(16) float zs[256][8];
    __shared__ float aA[8];
    __shared__ int   ln[8];
    __shared__ u64   wred[4 * 8];

    int tid = threadIdx.x, lane = tid & 63, w = tid >> 6;
    int count = *cnt;
    int ngroups = (count + 7) >> 3;

    for (int g = blockIdx.x; g < ngroups; g += gridDim.x) {
        __syncthreads();
#pragma unroll
        for (int r = 0; r < 8; r++) {
            int row = g * 8 + r;
            int n   = list[(row < count) ? row : 0];
            int b = n >> 11, t = n & 2047;
            zs[tid][r] = z[(size_t)b * (DD * TT) + (size_t)tid * TT + t];
            if (tid == 0) { ln[r] = (row < count) ? n : -1; aA[r] = A32[n]; }
        }
        __syncthreads();

        u64 best[8];
#pragma unroll
        for (int r = 0; r < 8; r++) best[r] = 0xFFFFFFFFFFFFFFFFull;

        float Ar[8];
#pragma unroll
        for (int r = 0; r < 8; r++) Ar[r] = aA[r];

        for (int c = 0; c < 8; c++) {
            int kbase = c * 1024 + tid;
            const float4* e0 = (const float4*)(emb + (size_t)(kbase)       * DD);
            const float4* e1 = (const float4*)(emb + (size_t)(kbase + 256) * DD);
            const float4* e2 = (const float4*)(emb + (size_t)(kbase + 512) * DD);
            const float4* e3 = (const float4*)(emb + (size_t)(kbase + 768) * DD);
            float acc[4][8];
#pragma unroll
            for (int qq = 0; qq < 4; qq++)
#pragma unroll
                for (int r = 0; r < 8; r++) acc[qq][r] = 0.0f;

#pragma unroll 2
            for (int d4 = 0; d4 < 64; d4++) {
                float4 v0 = e0[d4], v1 = e1[d4], v2 = e2[d4], v3 = e3[d4];
                const float* p0 = (const float*)&v0;
                const float* p1 = (const float*)&v1;
                const float* p2 = (const float*)&v2;
                const float* p3 = (const float*)&v3;
#pragma unroll
                for (int i = 0; i < 4; i++) {
                    int d = 4 * d4 + i;
                    float4 za = *(const float4*)&zs[d][0];
                    float4 zb2 = *(const float4*)&zs[d][4];
                    const float* zr  = (const float*)&za;
                    const float* zr2 = (const float*)&zb2;
#pragma unroll
                    for (int r = 0; r < 4; r++) {
                        acc[0][r]     = fmaf(zr[r],  p0[i], acc[0][r]);
                        acc[1][r]     = fmaf(zr[r],  p1[i], acc[1][r]);
                        acc[2][r]     = fmaf(zr[r],  p2[i], acc[2][r]);
                        acc[3][r]     = fmaf(zr[r],  p3[i], acc[3][r]);
                        acc[0][r + 4] = fmaf(zr2[r], p0[i], acc[0][r + 4]);
                        acc[1][r + 4] = fmaf(zr2[r], p1[i], acc[1][r + 4]);
                        acc[2][r + 4] = fmaf(zr2[r], p2[i], acc[2][r + 4]);
                        acc[3][r + 4] = fmaf(zr2[r], p3[i], acc[3][r + 4]);
                    }
                }
            }
#pragma unroll
            for (int qq = 0; qq < 4; qq++) {
                int k = kbase + qq * 256;
#pragma unroll
                for (int r = 0; r < 8; r++) {
                    float dk = Ar[r] - 2.0f * acc[qq][r];
                    u64 p = ((u64)mapf(dk) << 32) | (unsigned)k;
                    best[r] = (p < best[r]) ? p : best[r];
                }
            }
        }
#pragma unroll
        for (int r = 0; r < 8; r++) {
            u64 v = best[r];
            for (int off = 32; off; off >>= 1) {
                u64 o = __shfl_down(v, off, 64);
                v = (o < v) ? o : v;
            }
            if (lane == 0) wred[w * 8 + r] = v;
        }
        __syncthreads();
        if (tid < 8) {
            u64 v = wred[tid];
#pragma unroll
            for (int j = 1; j < 4; j++) {
                u64 o = wred[j * 8 + tid];
                v = (o < v) ? o : v;
            }
            int n = ln[tid];
            if (n >= 0) keys[n] = (int)(unsigned)(v & 0xFFFFFFFFull);
        }
        __syncthreads();
    }
}

// ---------------------------------------------------------------------------
// gather quantized, write outputs, loss = 1.25 * mean((q - z)^2)
// ---------------------------------------------------------------------------
__global__ __launch_bounds__(256) void k_out(const float* __restrict__ z,
                                             const float* __restrict__ emb,
                                             const int* __restrict__ keys,
                                             float* __restrict__ out) {
    int tid = threadIdx.x;
    int n   = blockIdx.x * 256 + tid;
    int b   = n >> 11;
    int t   = n & 2047;
    int idx = keys[n];
    out[QQ + 1 + n] = (float)idx;

    const float4* erow = (const float4*)(emb + (size_t)idx * DD);
    const float*  zp   = z   + (size_t)b * (DD * TT) + t;
    float*        op   = out + (size_t)b * (DD * TT) + t;

    float ssd = 0.0f;
#pragma unroll 4
    for (int d4 = 0; d4 < 64; d4++) {
        float4 qv = erow[d4];
        float qa[4] = {qv.x, qv.y, qv.z, qv.w};
#pragma unroll
        for (int r = 0; r < 4; r++) {
            int d = 4 * d4 + r;
            float zv = zp[(size_t)d * TT];
            float df = qa[r] - zv;
            ssd = fmaf(df, df, ssd);
            op[(size_t)d * TT] = qa[r];
        }
    }
    for (int off = 32; off; off >>= 1) ssd += __shfl_down(ssd, off, 64);
    __shared__ float red[4];
    if ((tid & 63) == 0) red[tid >> 6] = ssd;
    __syncthreads();
    if (tid == 0) {
        float tot = red[0] + red[1] + red[2] + red[3];
        atomicAdd(out + QQ, tot * (1.25f / (float)QQ));
    }
}

// ---------------------------------------------------------------------------
extern "C" void kernel_launch(void* const* d_in, const int* in_sizes, int n_in,
                              void* d_out, int out_size, void* d_ws, size_t ws_size,
                              hipStream_t stream) {
    const float* z   = (const float*)d_in[0];   // [16, 256, 2048]
    const float* emb = (const float*)d_in[1];   // [8192, 256]
    float* out = (float*)d_out;

    char* ws = (char*)d_ws;
    const size_t oZH = 0;
    const size_t oZL = oZH + 16777216;
    const size_t oEH = oZL + 16777216;
    const size_t oEL = oEH + 4194304;
    const size_t oCD = oEL + 4194304;          // cand: 8*32768*2*8 = 4 MB
    const size_t oA3 = oCD + 4194304;
    const size_t oKY = oA3 + 131072;
    const size_t oLS = oKY + 131072;
    const size_t oCN = oLS + 131072;
    const size_t needed = oCN + 64;

    if (ws_size >= needed) {
        unsigned short* zh = (unsigned short*)(ws + oZH);
        unsigned short* zl = (unsigned short*)(ws + oZL);
        unsigned short* eh = (unsigned short*)(ws + oEH);
        unsigned short* el = (unsigned short*)(ws + oEL);
        u64*   cand = (u64*)(ws + oCD);
        float* A32  = (float*)(ws + oA3);
        int*   keys = (int*)(ws + oKY);
        int*   list = (int*)(ws + oLS);
        int*   cnt  = (int*)(ws + oCN);

        k_prepA <<<512,  256, 0, stream>>>(z, A32, cnt, out);
        k_convZ <<<2048, 256, 0, stream>>>(z, zh, zl);
        k_convE <<<1024, 256, 0, stream>>>(emb, eh, el);
        k_gemm  <<<1024, 512, 0, stream>>>(zh, zl, eh, el, cand);
        k_select<<<2048, 256, 0, stream>>>(cand, z, emb, A32, keys, cnt, list);
        k_refine<<<512,  256, 0, stream>>>(z, emb, A32, list, cnt, keys);
        k_out   <<<128,  256, 0, stream>>>(z, emb, keys, out);
    } else {
        // fallback: round-3 proven path (~1.5 MB ws)
        u64*   cand2 = (u64*)ws;                          // 1 MB
        float* A32   = (float*)(ws + 1048576);            // 128 KB
        int*   keys  = (int*)(ws + 1048576 + 131072);
        int*   list  = (int*)(ws + 1048576 + 262144);
        int*   cnt   = (int*)(ws + 1048576 + 393216);

        k_prepA    <<<512,          256, 0, stream>>>(z, A32, cnt, out);
        k_argmin_fb<<<dim3(256, 2), 256, 0, stream>>>(z, emb, cand2);
        k_select_fb<<<128,          256, 0, stream>>>(cand2, A32, keys, cnt, list);
        k_refine   <<<512,          256, 0, stream>>>(z, emb, A32, list, cnt, keys);
        k_out      <<<128,          256, 0, stream>>>(z, emb, keys, out);
    }
}

// Round 9
// 801.925 us; speedup vs baseline: 1.4030x; 1.1596x over previous
//
#include <hip/hip_runtime.h>
#include <cstdint>

#define BB 16
#define DD 256
#define TT 2048
#define KK 8192
#define NN 32768            // BB*TT
#define QQ 8388608          // BB*DD*TT
typedef unsigned long long u64;

typedef __attribute__((ext_vector_type(8))) short short8;   // 8 bf16 (4 VGPRs)
typedef __attribute__((ext_vector_type(4))) float f32x4;    // MFMA C/D

#define GLOBAL_AS __attribute__((address_space(1)))
#define LDS_AS    __attribute__((address_space(3)))

// async global->LDS, 16 B per lane; LDS dest = wave-uniform base + lane*16
__device__ __forceinline__ void async_copy16(void* l, const void* g) {
    __builtin_amdgcn_global_load_lds((const GLOBAL_AS unsigned int*)g,
                                     (LDS_AS unsigned int*)l, 16, 0, 0);
}

__device__ __forceinline__ unsigned mapf(float f) {
    unsigned u = __float_as_uint(f);
    return (u & 0x80000000u) ? ~u : (u | 0x80000000u);
}
__device__ __forceinline__ float unmapf(unsigned u) {
    return __uint_as_float((u & 0x80000000u) ? (u & 0x7FFFFFFFu) : ~u);
}
__device__ __forceinline__ unsigned bf16_rne(float v) {
    unsigned ui = __float_as_uint(v);
    return (ui + 0x7FFFu + ((ui >> 16) & 1)) >> 16;
}

// ---------------------------------------------------------------------------
// A32[n] = fp32(fp64 sum of z_n^2); zero cnt & loss. grid 512 x 256
// ---------------------------------------------------------------------------
__global__ __launch_bounds__(256) void k_prepA(const float* __restrict__ z,
                                               float* __restrict__ A32,
                                               int* __restrict__ cnt,
                                               float* __restrict__ out) {
    __shared__ double sd[256];
    int tid = threadIdx.x;
    int r = tid & 63;               // row within block (coalesced over t)
    int c = tid >> 6;               // wave -> d quarter
    int n = blockIdx.x * 64 + r;
    if (blockIdx.x == 0 && tid == 0) { *cnt = 0; out[QQ] = 0.0f; }
    int b = n >> 11, t = n & 2047;
    const float* zp = z + (size_t)b * 524288 + t;
    double s = 0.0;
#pragma unroll 8
    for (int i = 0; i < 64; i++) {
        float v = zp[(size_t)(c * 64 + i) * 2048];
        s = fma((double)v, (double)v, s);
    }
    sd[tid] = s;
    __syncthreads();
    if (c == 0) {
        double tot = sd[r] + sd[64 + r] + sd[128 + r] + sd[192 + r];
        A32[n] = (float)tot;
    }
}

// ---------------------------------------------------------------------------
// z [b][d][t] fp32 -> zh/zl [n][d] bf16 hi/lo, 16B stores. grid 2048 x 256
// ---------------------------------------------------------------------------
__global__ __launch_bounds__(256) void k_convZ(const float* __restrict__ z,
                                               unsigned short* __restrict__ zh,
                                               unsigned short* __restrict__ zl) {
    __shared__ float sm[64][65];
    int tid = threadIdx.x;
    int bid = blockIdx.x;
    int b  = bid >> 7;
    int dt = (bid >> 5) & 3;
    int tt = bid & 31;
    const float* zp = z + (size_t)b * 524288 + (size_t)dt * 131072 + tt * 64;
#pragma unroll
    for (int i = 0; i < 16; i++) {
        int idx = tid + 256 * i;
        int d = idx >> 6, t = idx & 63;
        sm[d][t] = zp[(size_t)d * 2048 + t];
    }
    __syncthreads();
    int d0 = (tid & 7) * 8;
#pragma unroll
    for (int i = 0; i < 2; i++) {
        int t = (tid >> 3) + 32 * i;
        size_t o = ((size_t)(b * 2048 + tt * 64 + t)) * 256 + dt * 64 + d0;
        short8 hv, lv;
#pragma unroll
        for (int j = 0; j < 8; j++) {
            float v = sm[d0 + j][t];
            unsigned hb = bf16_rne(v);
            float hf = __uint_as_float(hb << 16);
            unsigned lb = bf16_rne(v - hf);
            hv[j] = (short)hb;
            lv[j] = (short)lb;
        }
        *(short8*)(zh + o) = hv;
        *(short8*)(zl + o) = lv;
    }
}

// ---------------------------------------------------------------------------
// emb [k][d] fp32 -> eh/el bf16 hi/lo. grid 1024 x 256
// ---------------------------------------------------------------------------
__global__ __launch_bounds__(256) void k_convE(const float* __restrict__ emb,
                                               unsigned short* __restrict__ eh,
                                               unsigned short* __restrict__ el) {
    int base = (blockIdx.x * 256 + threadIdx.x) * 8;
    float4 v0 = *(const float4*)(emb + base);
    float4 v1 = *(const float4*)(emb + base + 4);
    float vv[8] = {v0.x, v0.y, v0.z, v0.w, v1.x, v1.y, v1.z, v1.w};
    short8 hv, lv;
#pragma unroll
    for (int i = 0; i < 8; i++) {
        unsigned hb = bf16_rne(vv[i]);
        float hf = __uint_as_float(hb << 16);
        unsigned lb = bf16_rne(vv[i] - hf);
        hv[i] = (short)hb;
        lv[i] = (short)lb;
    }
    *(short8*)(eh + base) = hv;
    *(short8*)(el + base) = lv;
}

// ---------------------------------------------------------------------------
// MFMA distance GEMM v10: score = -2*(zh.eh + zh.el + zl.eh)
// v9 structure UNCHANGED (256x1024 block, 8 waves, wave tile 64x128, all-LDS
// staging, BK=32 dbuf, single barrier/K-step). Fold upgraded to per-ng TOP-3:
// #1,#2 with index (packed i1|i2<<16: zero register delta vs v9), #3 value
// only (guard certificate). cand: 3 u64/row/ng; entry 2 carries idx=0xFFFFFFFF
// and provably never lands in slot 0/1 of any merge (it is the max of its
// own triple, so >=2 real entries sort below it).
// grid 1024 (tl = (bid&7)*128 + bid>>3; mt = tl>>3, ng = tl&7).
// ---------------------------------------------------------------------------
__global__ __launch_bounds__(512, 2) void k_gemm(const unsigned short* __restrict__ zh,
                                                 const unsigned short* __restrict__ zl,
                                                 const unsigned short* __restrict__ eh,
                                                 const unsigned short* __restrict__ el,
                                                 u64* __restrict__ cand) {
    __shared__ __align__(16) unsigned short pool[2][32768];   // 128 KB

    int tid  = threadIdx.x;
    int w    = __builtin_amdgcn_readfirstlane(tid >> 6);   // wave id (uniform)
    int lane = tid & 63;
    int lm   = lane & 15;
    int q    = lane >> 4;
    int wm   = w >> 1;              // 0..3: 64-row group
    int wn   = w & 1;               // 0..1: 128-code half

    int bid = blockIdx.x;
    int tl  = (bid & 7) * 128 + (bid >> 3);   // XCD-chunked (1024 % 8 == 0)
    int mt  = tl >> 3;              // 0..127: 256-row tile
    int ng  = tl & 7;               // 0..7  : 1024-code group

    // ---- staging: 8 copies/wave; slot = w*8+i -> (arr = slot>>4, tile = slot&15)
    int laneoff = lm * 256 + q * 8;          // per-lane (row, k-chunk) offset
    const unsigned short* gp[8];
    unsigned dlo[8];
    bool bflag[8];
#pragma unroll
    for (int i = 0; i < 8; i++) {
        int slot = w * 8 + i;
        int arr  = slot >> 4;
        int tile = slot & 15;
        const unsigned short* s = (arr == 0) ? zh : (arr == 1) ? zl
                                : (arr == 2) ? eh : el;
        int rowb = (arr < 2) ? mt * 256 : ng * 1024;
        gp[i]    = s + (size_t)(rowb + tile * 16) * 256 + laneoff;
        dlo[i]   = (unsigned)(arr * 8192 + tile * 512);
        bflag[i] = (arr >= 2);
    }

    // float-domain top-3 per (mi,reg): track MAX of acc (score = -2*acc).
    // #1,#2 carry indices (packed 16+16 bits); #3 value-only.
    float v1a[4][4], v2a[4][4], v3a[4][4];
    unsigned i12a[4][4];
#pragma unroll
    for (int mi = 0; mi < 4; mi++)
#pragma unroll
        for (int reg = 0; reg < 4; reg++) {
            v1a[mi][reg] = -3.4e38f; v2a[mi][reg] = -3.4e38f;
            v3a[mi][reg] = -3.4e38f; i12a[mi][reg] = 0;
        }

    f32x4 acc[4][8];

    // prologue: stage k-tile 0 into buffer 0
#pragma unroll
    for (int i = 0; i < 8; i++)
        async_copy16(&pool[0][dlo[i]], gp[i]);

    for (int t = 0; t < 32; ++t) {            // 4 passes x 8 K-steps
        int buf = t & 1;
        int kc  = t & 7;

        // stage(t) was issued one full compute window ago -> drain is cheap
        asm volatile("s_waitcnt vmcnt(0)" ::: "memory");
        __builtin_amdgcn_s_barrier();          // buf complete + prior readers done
        __builtin_amdgcn_sched_barrier(0);

        int tn = t + 1;
        if (tn < 32) {
            if ((tn & 7) == 0) {               // next stage starts a new 256-code pass
#pragma unroll
                for (int i = 0; i < 8; i++)
                    if (bflag[i]) gp[i] += 65536;   // +256 codes
            }
            int nkc = tn & 7;
#pragma unroll
            for (int i = 0; i < 8; i++)
                async_copy16(&pool[buf ^ 1][dlo[i]], gp[i] + nkc * 32);
        }

        if (kc == 0) {
#pragma unroll
            for (int mi = 0; mi < 4; mi++)
#pragma unroll
                for (int ni = 0; ni < 8; ni++) acc[mi][ni] = (f32x4){0.f, 0.f, 0.f, 0.f};
        }

        const unsigned short* pb = pool[buf];
        short8 azh[4], azl[4];
#pragma unroll
        for (int mi = 0; mi < 4; mi++) {
            azh[mi] = *(const short8*)&pb[(wm * 4 + mi) * 512 + lane * 8];
            azl[mi] = *(const short8*)&pb[8192 + (wm * 4 + mi) * 512 + lane * 8];
        }
        __builtin_amdgcn_s_setprio(1);
#pragma unroll
        for (int ni = 0; ni < 8; ni++) {
            short8 bh = *(const short8*)&pb[16384 + (wn * 8 + ni) * 512 + lane * 8];
            short8 bl = *(const short8*)&pb[24576 + (wn * 8 + ni) * 512 + lane * 8];
#pragma unroll
            for (int mi = 0; mi < 4; mi++) {
                acc[mi][ni] = __builtin_amdgcn_mfma_f32_16x16x32_bf16(azh[mi], bh, acc[mi][ni], 0, 0, 0);
                acc[mi][ni] = __builtin_amdgcn_mfma_f32_16x16x32_bf16(azl[mi], bh, acc[mi][ni], 0, 0, 0);
                acc[mi][ni] = __builtin_amdgcn_mfma_f32_16x16x32_bf16(azh[mi], bl, acc[mi][ni], 0, 0, 0);
            }
        }
        __builtin_amdgcn_s_setprio(0);

        if (kc == 7) {   // pass complete: fold 256 codes into per-lane top-3
            int idb = ng * 1024 + (t >> 3) * 256 + wn * 128 + lm;
#pragma unroll
            for (int ni = 0; ni < 8; ni++) {
                unsigned id = (unsigned)(idb + ni * 16);
#pragma unroll
                for (int mi = 0; mi < 4; mi++)
#pragma unroll
                    for (int reg = 0; reg < 4; reg++) {
                        float v = acc[mi][ni][reg];
                        bool c3 = v > v3a[mi][reg];
                        bool c2 = v > v2a[mi][reg];
                        bool c1 = v > v1a[mi][reg];
                        v3a[mi][reg] = c3 ? v : v3a[mi][reg];
                        v3a[mi][reg] = c2 ? v2a[mi][reg] : v3a[mi][reg];
                        v2a[mi][reg] = c2 ? v : v2a[mi][reg];
                        v2a[mi][reg] = c1 ? v1a[mi][reg] : v2a[mi][reg];
                        v1a[mi][reg] = c1 ? v : v1a[mi][reg];
                        unsigned iv  = i12a[mi][reg];
                        unsigned i1o = iv & 0xFFFFu;
                        unsigned i2n = c2 ? (c1 ? i1o : id) : (iv >> 16);
                        unsigned i1n = c1 ? id : i1o;
                        i12a[mi][reg] = i1n | (i2n << 16);
                    }
            }
        }
        // no end barrier: next iteration's top barrier protects the restage
    }

    // pack to mapf-u64 triples, butterfly across the 16 lm-lanes via
    // insert-merge; rtop aliases pool[0] (fenced by the t=31 barrier).
    u64* rtop = (u64*)&pool[0][0];
#pragma unroll
    for (int mi = 0; mi < 4; mi++)
#pragma unroll
        for (int reg = 0; reg < 4; reg++) {
            unsigned iv = i12a[mi][reg];
            u64 p1 = ((u64)mapf(-2.0f * v1a[mi][reg]) << 32) | (iv & 0xFFFFu);
            u64 p2 = ((u64)mapf(-2.0f * v2a[mi][reg]) << 32) | (iv >> 16);
            u64 p3 = ((u64)mapf(-2.0f * v3a[mi][reg]) << 32) | 0xFFFFFFFFull;
#pragma unroll
            for (int msk = 1; msk <= 8; msk <<= 1) {
                u64 q1 = __shfl_xor(p1, msk, 64);
                u64 q2 = __shfl_xor(p2, msk, 64);
                u64 q3 = __shfl_xor(p3, msk, 64);
#pragma unroll
                for (int s = 0; s < 3; s++) {
                    u64 x = (s == 0) ? q1 : (s == 1) ? q2 : q3;
                    bool lt3 = x < p3, lt2 = x < p2, lt1 = x < p1;
                    p3 = lt3 ? x : p3;  p3 = lt2 ? p2 : p3;
                    p2 = lt2 ? x : p2;  p2 = lt1 ? p1 : p2;
                    p1 = lt1 ? x : p1;
                }
            }
            if (lm == 0) {
                int rl = wm * 64 + mi * 16 + q * 4 + reg;   // 0..255 block row
                rtop[rl * 6 + wn * 3]     = p1;
                rtop[rl * 6 + wn * 3 + 1] = p2;
                rtop[rl * 6 + wn * 3 + 2] = p3;
            }
        }
    __syncthreads();
    if (tid < 256) {   // merge the two code-halves for each row
        u64 p1 = rtop[tid * 6],     p2 = rtop[tid * 6 + 1], p3 = rtop[tid * 6 + 2];
        u64 b1 = rtop[tid * 6 + 3], b2 = rtop[tid * 6 + 4], b3 = rtop[tid * 6 + 5];
#pragma unroll
        for (int s = 0; s < 3; s++) {
            u64 x = (s == 0) ? b1 : (s == 1) ? b2 : b3;
            bool lt3 = x < p3, lt2 = x < p2, lt1 = x < p1;
            p3 = lt3 ? x : p3;  p3 = lt2 ? p2 : p3;
            p2 = lt2 ? x : p2;  p2 = lt1 ? p1 : p2;
            p1 = lt1 ? x : p1;
        }
        size_t o = ((size_t)ng * 32768 + (size_t)mt * 256 + tid) * 3;
        cand[o]     = p1;
        cand[o + 1] = p2;
        cand[o + 2] = p3;
    }
}

// ---------------------------------------------------------------------------
// select v4 (top-3 guard + lane-parallel rescore): 32 lanes per row; lane
// c<24 holds entry (ng = c/3, rank = c%3). Guard: no ng's #3 (value-only)
// within W of the global bf-min => every window code is in some ng's top-2
// => the 16 rank<2 entries contain all fp32-minimal codes (|bf-fp32|<=W/2);
// exact fp32 rescore (reference serial-d order) + lexicographic min then
// reproduces the full scan. Guard violated -> rkey=~0 + list for full refine.
// Writes packed (dist,idx) u64 to rkey. grid 4096 x 256 (8 rows/block).
// ---------------------------------------------------------------------------
__global__ __launch_bounds__(256) void k_select(const u64* __restrict__ cand,
                                                const float* __restrict__ z,
                                                const float* __restrict__ emb,
                                                const float* __restrict__ A32,
                                                u64* __restrict__ rkey,
                                                int* __restrict__ cnt,
                                                int* __restrict__ list) {
    int tid = threadIdx.x;
    int g   = tid >> 5;              // row within block (0..7)
    int c   = tid & 31;              // lane within row-group
    int n   = blockIdx.x * 8 + g;

    int cc   = (c < 24) ? c : 0;
    int ngj  = cc / 3;
    int rank = cc - ngj * 3;
    u64 e = cand[((size_t)ngj * 32768 + n) * 3 + rank];

    // group-min over entries = global bf top-1 (#3 dummies can't win: each is
    // >= its ng's #1, and on equal score the 0xFFFFFFFF idx sorts larger)
    u64 m1 = e;
#pragma unroll
    for (int m = 1; m < 32; m <<= 1) {
        u64 o = __shfl_xor(m1, m, 64);
        m1 = (o < m1) ? o : m1;
    }
    float f1   = unmapf((unsigned)(m1 >> 32));
    float A32v = A32[n];
    float W = ((A32v >= 255.9f) ? 3.4e-5f : 1.8e-5f) + 4e-6f;  // + 2*eps(bf16x3)

    // guard: any ng's #3 within window -> full refine
    int fl = (c < 24 && rank == 2 && (unmapf((unsigned)(e >> 32)) - f1 <= W)) ? 1 : 0;
#pragma unroll
    for (int m = 1; m < 32; m <<= 1) fl |= __shfl_xor(fl, m, 64);

    if (fl) {
        if (c == 0) {
            rkey[n] = ~0ull;                 // refine fills via atomicMin
            int p = atomicAdd(cnt, 1);
            list[p] = n;
        }
        return;
    }

    // exact fp32 rescore of the 16 rank<2 candidates (reference order)
    bool valid = (c < 24) && (rank < 2);
    int idx = valid ? (int)(unsigned)(e & 0xFFFFFFFFull) : 0;
    int b = n >> 11, t = n & 2047;
    const float* zp = z + (size_t)b * 524288 + t;
    const float* ep = emb + (size_t)idx * 256;
    float acc = 0.0f;
#pragma unroll 4
    for (int d = 0; d < 256; d++)
        acc = fmaf(zp[(size_t)d * 2048], ep[d], acc);
    float dk = A32v - 2.0f * acc;
    u64 best = valid ? (((u64)mapf(dk) << 32) | (unsigned)idx) : ~0ull;
#pragma unroll
    for (int m = 1; m < 32; m <<= 1) {
        u64 o = __shfl_xor(best, m, 64);
        best = (o < best) ? o : best;
    }
    if (c == 0) rkey[n] = best;
}

// ---------------------------------------------------------------------------
// FALLBACK path (round-3 proven): fp32 VALU GEMM argmin + its select
// ---------------------------------------------------------------------------
__global__ __launch_bounds__(256) void k_argmin_fb(const float* __restrict__ z,
                                                   const float* __restrict__ emb,
                                                   u64* __restrict__ cand2) {
    __shared__ __align__(16) float smem[8192];
    float* As = smem;
    float* Bs = smem + 4096;

    int tid = threadIdx.x;
    int tx  = tid & 15;
    int ty  = tid >> 4;
    int mt  = blockIdx.x;
    int kh  = blockIdx.y;

    int bimg = mt >> 4;
    int t0   = (mt & 15) << 7;
    const float* zb = z + (size_t)bimg * (DD * TT) + t0;

    float bestv[8], bestv2[8];
    int   besti[8];
#pragma unroll
    for (int i = 0; i < 8; i++) { bestv[i] = 3.4e38f; bestv2[i] = 3.4e38f; besti[i] = 0; }

    int qa = tid & 31, ra = tid >> 5;
    int jb = tid >> 3, db = tid & 7;
    int swz_t = (tx & 7) << 2;

    for (int kc = 0; kc < 32; kc++) {
        int k0 = kh * 4096 + kc * 128;
        float acc[8][8];
#pragma unroll
        for (int i = 0; i < 8; i++)
#pragma unroll
            for (int j = 0; j < 8; j++) acc[i][j] = 0.0f;

        for (int dc = 0; dc < 8; dc++) {
            int d0 = dc * 32;
            __syncthreads();
#pragma unroll
            for (int s = 0; s < 4; s++) {
                int d = ra + 8 * s;
                float4 v = *(const float4*)(zb + (size_t)(d0 + d) * TT + 4 * qa);
                *(float4*)(As + d * 128 + 4 * qa) = v;
            }
#pragma unroll
            for (int s = 0; s < 4; s++) {
                int row = jb + 32 * s;
                float4 v = *(const float4*)(emb + (size_t)(k0 + row) * DD + d0 + 4 * db);
                int col  = (4 * db) ^ ((row & 7) << 2);
                *(float4*)(Bs + row * 32 + col) = v;
            }
            __syncthreads();
#pragma unroll
            for (int g = 0; g < 8; g++) {
                float4 bf[8];
#pragma unroll
                for (int in = 0; in < 8; in++) {
                    int nn = in * 16 + tx;
                    bf[in] = *(const float4*)(Bs + nn * 32 + ((4 * g) ^ swz_t));
                }
#pragma unroll
                for (int j = 0; j < 4; j++) {
                    int d = 4 * g + j;
                    float4 a0 = *(const float4*)(As + d * 128 + ty * 8);
                    float4 a1 = *(const float4*)(As + d * 128 + ty * 8 + 4);
                    float av[8] = {a0.x, a0.y, a0.z, a0.w, a1.x, a1.y, a1.z, a1.w};
#pragma unroll
                    for (int im = 0; im < 8; im++) {
#pragma unroll
                        for (int in = 0; in < 8; in++) {
                            const float* bfp = (const float*)&bf[in];
                            acc[im][in] = fmaf(av[im], bfp[j], acc[im][in]);
                        }
                    }
                }
            }
        }
#pragma unroll
        for (int in = 0; in < 8; in++) {
            int k = k0 + in * 16 + tx;
#pragma unroll
            for (int im = 0; im < 8; im++) {
                float s = -2.0f * acc[im][in];
                if (s < bestv[im]) { bestv2[im] = bestv[im]; bestv[im] = s; besti[im] = k; }
                else if (s < bestv2[im]) { bestv2[im] = s; }
            }
        }
    }

    __syncthreads();
    u64* red = (u64*)smem;
#pragma unroll
    for (int im = 0; im < 8; im++) {
        int r = ty * 8 + im;
        red[r * 32 + tx * 2 + 0] = ((u64)mapf(bestv[im]) << 32) | (unsigned)besti[im];
        red[r * 32 + tx * 2 + 1] = ((u64)mapf(bestv2[im]) << 32);
    }
    __syncthreads();
    if (tid < 128) {
        const u64* base = red + tid * 32;
        u64 p1 = base[0];
        u64 s2 = base[1];
#pragma unroll
        for (int t = 1; t < 16; t++) {
            u64 c1 = base[t * 2], c2 = base[t * 2 + 1];
            if (c1 < p1) { s2 = (p1 < s2) ? p1 : s2; p1 = c1; }
            else         { s2 = (c1 < s2) ? c1 : s2; }
            s2 = (c2 < s2) ? c2 : s2;
        }
        int n = mt * 128 + tid;
        cand2[(size_t)n * 4 + kh * 2]     = p1;
        cand2[(size_t)n * 4 + kh * 2 + 1] = s2;
    }
}

__global__ __launch_bounds__(256) void k_select_fb(const u64* __restrict__ cand2,
                                                   const float* __restrict__ A32,
                                                   u64* __restrict__ rkey,
                                                   int* __restrict__ cnt,
                                                   int* __restrict__ list) {
    int n = blockIdx.x * 256 + threadIdx.x;
    u64 a1 = cand2[(size_t)n * 4 + 0], a2 = cand2[(size_t)n * 4 + 1];
    u64 b1 = cand2[(size_t)n * 4 + 2], b2 = cand2[(size_t)n * 4 + 3];
    u64 m1 = (a1 < b1) ? a1 : b1;
    u64 lo = (a1 < b1) ? b1 : a1;
    u64 m2 = (a2 < b2) ? a2 : b2;
    m2 = (lo < m2) ? lo : m2;

    float f1 = unmapf((unsigned)(m1 >> 32));
    float f2 = unmapf((unsigned)(m2 >> 32));
    float W = (A32[n] >= 255.9f) ? 3.4e-5f : 1.8e-5f;
    if (f2 - f1 <= W) {
        rkey[n] = ~0ull;
        int p = atomicAdd(cnt, 1);
        list[p] = n;
    } else {
        rkey[n] = m1;
    }
}

// ---------------------------------------------------------------------------
// exact np-fp32 emulation for flagged rows, 4-way code-chunked: block
// (g = bid>>2, chunk = bid&3) scans codes [chunk*2048, +2048) for group g's
// 8 rows and atomicMins the packed (dist,idx) into rkey. Per-code value and
// accumulation order identical to the full scan -> min over chunks == full
// scan (distinct idx => total order). grid 2048 x 256.
// ---------------------------------------------------------------------------
__global__ __launch_bounds__(256) void k_refine(const float* __restrict__ z,
                                                const float* __restrict__ emb,
                                                const float* __restrict__ A32,
                                                const int* __restrict__ list,
                                                const int* __restrict__ cnt,
                                                u64* __restrict__ rkey) {
    __shared__ __align__(16) float zs[256][8];
    __shared__ float aA[8];
    __shared__ int   ln[8];
    __shared__ u64   wred[4 * 8];

    int tid = threadIdx.x, lane = tid & 63, w = tid >> 6;
    int count = *cnt;
    int ngroups = (count + 7) >> 3;
    int ch2 = (blockIdx.x & 3) * 2;          // chunk -> c in {ch2, ch2+1}

    for (int g = blockIdx.x >> 2; g < ngroups; g += 512) {
        __syncthreads();
#pragma unroll
        for (int r = 0; r < 8; r++) {
            int row = g * 8 + r;
            int n   = list[(row < count) ? row : 0];
            int b = n >> 11, t = n & 2047;
            zs[tid][r] = z[(size_t)b * (DD * TT) + (size_t)tid * TT + t];
            if (tid == 0) { ln[r] = (row < count) ? n : -1; aA[r] = A32[n]; }
        }
        __syncthreads();

        u64 best[8];
#pragma unroll
        for (int r = 0; r < 8; r++) best[r] = 0xFFFFFFFFFFFFFFFFull;

        float Ar[8];
#pragma unroll
        for (int r = 0; r < 8; r++) Ar[r] = aA[r];

        for (int c = ch2; c < ch2 + 2; c++) {
            int kbase = c * 1024 + tid;
            const float4* e0 = (const float4*)(emb + (size_t)(kbase)       * DD);
            const float4* e1 = (const float4*)(emb + (size_t)(kbase + 256) * DD);
            const float4* e2 = (const float4*)(emb + (size_t)(kbase + 512) * DD);
            const float4* e3 = (const float4*)(emb + (size_t)(kbase + 768) * DD);
            float acc[4][8];
#pragma unroll
            for (int qq = 0; qq < 4; qq++)
#pragma unroll
                for (int r = 0; r < 8; r++) acc[qq][r] = 0.0f;

#pragma unroll 2
            for (int d4 = 0; d4 < 64; d4++) {
                float4 v0 = e0[d4], v1 = e1[d4], v2 = e2[d4], v3 = e3[d4];
                const float* p0 = (const float*)&v0;
                const float* p1 = (const float*)&v1;
                const float* p2 = (const float*)&v2;
                const float* p3 = (const float*)&v3;
#pragma unroll
                for (int i = 0; i < 4; i++) {
                    int d = 4 * d4 + i;
                    float4 za = *(const float4*)&zs[d][0];
                    float4 zb2 = *(const float4*)&zs[d][4];
                    const float* zr  = (const float*)&za;
                    const float* zr2 = (const float*)&zb2;
#pragma unroll
                    for (int r = 0; r < 4; r++) {
                        acc[0][r]     = fmaf(zr[r],  p0[i], acc[0][r]);
                        acc[1][r]     = fmaf(zr[r],  p1[i], acc[1][r]);
                        acc[2][r]     = fmaf(zr[r],  p2[i], acc[2][r]);
                        acc[3][r]     = fmaf(zr[r],  p3[i], acc[3][r]);
                        acc[0][r + 4] = fmaf(zr2[r], p0[i], acc[0][r + 4]);
                        acc[1][r + 4] = fmaf(zr2[r], p1[i], acc[1][r + 4]);
                        acc[2][r + 4] = fmaf(zr2[r], p2[i], acc[2][r + 4]);
                        acc[3][r + 4] = fmaf(zr2[r], p3[i], acc[3][r + 4]);
                    }
                }
            }
#pragma unroll
            for (int qq = 0; qq < 4; qq++) {
                int k = kbase + qq * 256;
#pragma unroll
                for (int r = 0; r < 8; r++) {
                    float dk = Ar[r] - 2.0f * acc[qq][r];
                    u64 p = ((u64)mapf(dk) << 32) | (unsigned)k;
                    best[r] = (p < best[r]) ? p : best[r];
                }
            }
        }
#pragma unroll
        for (int r = 0; r < 8; r++) {
            u64 v = best[r];
            for (int off = 32; off; off >>= 1) {
                u64 o = __shfl_down(v, off, 64);
                v = (o < v) ? o : v;
            }
            if (lane == 0) wred[w * 8 + r] = v;
        }
        __syncthreads();
        if (tid < 8) {
            u64 v = wred[tid];
#pragma unroll
            for (int j = 1; j < 4; j++) {
                u64 o = wred[j * 8 + tid];
                v = (o < v) ? o : v;
            }
            int n = ln[tid];
            if (n >= 0) atomicMin((unsigned long long*)&rkey[n], v);
        }
        __syncthreads();
    }
}

// ---------------------------------------------------------------------------
// gather quantized, write outputs, loss = 1.25 * mean((q - z)^2)
// ---------------------------------------------------------------------------
__global__ __launch_bounds__(256) void k_out(const float* __restrict__ z,
                                             const float* __restrict__ emb,
                                             const u64* __restrict__ rkey,
                                             float* __restrict__ out) {
    int tid = threadIdx.x;
    int n   = blockIdx.x * 256 + tid;
    int b   = n >> 11;
    int t   = n & 2047;
    int idx = (int)(unsigned)(rkey[n] & 0xFFFFFFFFull);
    out[QQ + 1 + n] = (float)idx;

    const float4* erow = (const float4*)(emb + (size_t)idx * DD);
    const float*  zp   = z   + (size_t)b * (DD * TT) + t;
    float*        op   = out + (size_t)b * (DD * TT) + t;

    float ssd = 0.0f;
#pragma unroll 4
    for (int d4 = 0; d4 < 64; d4++) {
        float4 qv = erow[d4];
        float qa[4] = {qv.x, qv.y, qv.z, qv.w};
#pragma unroll
        for (int r = 0; r < 4; r++) {
            int d = 4 * d4 + r;
            float zv = zp[(size_t)d * TT];
            float df = qa[r] - zv;
            ssd = fmaf(df, df, ssd);
            op[(size_t)d * TT] = qa[r];
        }
    }
    for (int off = 32; off; off >>= 1) ssd += __shfl_down(ssd, off, 64);
    __shared__ float red[4];
    if ((tid & 63) == 0) red[tid >> 6] = ssd;
    __syncthreads();
    if (tid == 0) {
        float tot = red[0] + red[1] + red[2] + red[3];
        atomicAdd(out + QQ, tot * (1.25f / (float)QQ));
    }
}

// ---------------------------------------------------------------------------
extern "C" void kernel_launch(void* const* d_in, const int* in_sizes, int n_in,
                              void* d_out, int out_size, void* d_ws, size_t ws_size,
                              hipStream_t stream) {
    const float* z   = (const float*)d_in[0];   // [16, 256, 2048]
    const float* emb = (const float*)d_in[1];   // [8192, 256]
    float* out = (float*)d_out;

    char* ws = (char*)d_ws;
    const size_t oZH = 0;
    const size_t oZL = oZH + 16777216;
    const size_t oEH = oZL + 16777216;
    const size_t oEL = oEH + 4194304;
    const size_t oCD = oEL + 4194304;          // cand: 3*8*32768*8 = 6 MB
    const size_t oRK = oCD + 6291456;          // rkey: 32768*8 = 256 KB
    const size_t oA3 = oRK + 262144;
    const size_t oLS = oA3 + 131072;
    const size_t oCN = oLS + 131072;
    const size_t needed = oCN + 64;

    if (ws_size >= needed) {
        unsigned short* zh = (unsigned short*)(ws + oZH);
        unsigned short* zl = (unsigned short*)(ws + oZL);
        unsigned short* eh = (unsigned short*)(ws + oEH);
        unsigned short* el = (unsigned short*)(ws + oEL);
        u64*   cand = (u64*)(ws + oCD);
        u64*   rkey = (u64*)(ws + oRK);
        float* A32  = (float*)(ws + oA3);
        int*   list = (int*)(ws + oLS);
        int*   cnt  = (int*)(ws + oCN);

        k_prepA <<<512,  256, 0, stream>>>(z, A32, cnt, out);
        k_convZ <<<2048, 256, 0, stream>>>(z, zh, zl);
        k_convE <<<1024, 256, 0, stream>>>(emb, eh, el);
        k_gemm  <<<1024, 512, 0, stream>>>(zh, zl, eh, el, cand);
        k_select<<<4096, 256, 0, stream>>>(cand, z, emb, A32, rkey, cnt, list);
        k_refine<<<2048, 256, 0, stream>>>(z, emb, A32, list, cnt, rkey);
        k_out   <<<128,  256, 0, stream>>>(z, emb, rkey, out);
    } else {
        // fallback: round-3 proven path (~1.6 MB ws)
        u64*   cand2 = (u64*)ws;                          // 1 MB
        float* A32   = (float*)(ws + 1048576);            // 128 KB
        u64*   rkey  = (u64*)(ws + 1048576 + 131072);     // 256 KB
        int*   list  = (int*)(ws + 1048576 + 131072 + 262144);
        int*   cnt   = (int*)(ws + 1048576 + 131072 + 262144 + 131072);

        k_prepA    <<<512,          256, 0, stream>>>(z, A32, cnt, out);
        k_argmin_fb<<<dim3(256, 2), 256, 0, stream>>>(z, emb, cand2);
        k_select_fb<<<128,          256, 0, stream>>>(cand2, A32, rkey, cnt, list);
        k_refine   <<<2048,         256, 0, stream>>>(z, emb, A32, list, cnt, rkey);
        k_out      <<<128,          256, 0, stream>>>(z, emb, rkey, out);
    }
}